// Round 3
// baseline (288.487 us; speedup 1.0000x reference)
//
#include <hip/hip_runtime.h>

// SSIM, N=32 images 512x512 fp32, 11x11 Gaussian (separable via rank-1
// window), zero pad, scalar mean output.
//
// R3: latency-focused rework. 256-thread blocks own a full 512-col row
// (M=2 cols/thread); RROWS=16 rows/block -> 1024 blocks = 4096 waves =
// 4 waves/SIMD (__launch_bounds__(256,4)). Per row: prefetched coalesced
// float2 global loads (one row ahead), LDS double-buffered staging
// (1 barrier/row), window = 7x ds_read_b64 per plane with static
// extraction (flat offset 1+j is thread-independent), products p=x^2+y^2,
// q=x*y once per element, scatter-FMA horizontal conv, register-ring
// vertical conv (mod-11 static via 11x unroll), SSIM epilogue, wave
// shuffle reduce, one atomicAdd per wave.

#define IMG_H 512
#define IMG_W 512
#define NIMG  32
#define NT    256
#define RROWS 16
#define ITERS (RROWS + 10)   // 26 input rows streamed per chunk
#define LDSW  528            // 8 zero-pad + 512 + 8 zero-pad

#define C1F  1.0e-4f
#define C2F  9.0e-4f
#define EPSF 1.0e-8f

__global__ __launch_bounds__(NT, 4) void ssim_kernel(
    const float* __restrict__ xg, const float* __restrict__ yg,
    const float* __restrict__ wg, float* __restrict__ out)
{
    const int t    = threadIdx.x;         // 0..255
    const int lane = t & 63;
    const int chnk = blockIdx.x;          // 0..31
    const int img  = blockIdx.y;          // 0..31
    const int r0   = chnk * RROWS;
    const int c0   = 2 * t;               // own columns c0, c0+1

    const float* xb = xg + (size_t)img * (IMG_H * IMG_W);
    const float* yb = yg + (size_t)img * (IMG_H * IMG_W);

    __shared__ float sx[2][LDSW];
    __shared__ float sy[2][LDSW];

    // 1D taps = row sums of normalized 2D window; every wave computes its
    // own copy (no barrier needed), broadcast to SGPRs via readfirstlane.
    float rs = 0.f;
    if (lane < 11) {
        #pragma unroll
        for (int j = 0; j < 11; ++j) rs += wg[lane * 11 + j];
    }
    float g[11];
    #pragma unroll
    for (int k = 0; k < 11; ++k) {
        int gi = __shfl(__float_as_int(rs), k, 64);
        g[k] = __int_as_float(__builtin_amdgcn_readfirstlane(gi));
    }

    // zero the halo pads once (both buffers); visible after first barrier
    if (t < 8) {
        sx[0][t] = 0.f; sx[1][t] = 0.f;
        sy[0][t] = 0.f; sy[1][t] = 0.f;
    } else if (t < 16) {
        sx[0][512 + t] = 0.f; sx[1][512 + t] = 0.f;   // idx 520..527
        sy[0][512 + t] = 0.f; sy[1][512 + t] = 0.f;
    }

    // vertical register rings: 4 planes x 2 cols x 11 rows = 88 VGPRs
    float rxA[11], rxB[11], ryA[11], ryB[11];
    float rpA[11], rpB[11], rqA[11], rqB[11];

    const float2 z2 = make_float2(0.f, 0.f);

    // preload first input row (r0 - 5)
    float2 pfx, pfy;
    {
        const int r = r0 - 5;
        if ((unsigned)r < IMG_H) {
            pfx = *(const float2*)(xb + (size_t)r * IMG_W + c0);
            pfy = *(const float2*)(yb + (size_t)r * IMG_W + c0);
        } else { pfx = z2; pfy = z2; }
    }

    float acc = 0.f;

    for (int ii = 0; ii < 33; ii += 11) {
        #pragma unroll
        for (int s = 0; s < 11; ++s) {
            const int i = ii + s;
            if (i < ITERS) {
                const int pb = i & 1;
                *(float2*)&sx[pb][8 + c0] = pfx;
                *(float2*)&sy[pb][8 + c0] = pfy;
                __syncthreads();

                // prefetch next row (consumed next iteration)
                {
                    const int r = r0 - 4 + i;
                    if ((unsigned)r < IMG_H) {
                        pfx = *(const float2*)(xb + (size_t)r * IMG_W + c0);
                        pfy = *(const float2*)(yb + (size_t)r * IMG_W + c0);
                    } else { pfx = z2; pfy = z2; }
                }

                // window: cols c0-5 .. c0+6 -> lds idx c0+3 .. c0+14,
                // read as 7 aligned float2 pairs starting at even idx c0+2.
                float2 wx[7], wy[7];
                #pragma unroll
                for (int p = 0; p < 7; ++p) {
                    wx[p] = *(const float2*)&sx[pb][c0 + 2 + 2 * p];
                    wy[p] = *(const float2*)&sy[pb][c0 + 2 + 2 * p];
                }

                // fused prep + scatter horizontal conv.
                // elem j (=0..11) is col c0-5+j, flat pair offset o=1+j:
                // pair p=o>>1, comp o&1 — static for all threads.
                float hxA = 0.f, hxB = 0.f, hyA = 0.f, hyB = 0.f;
                float hpA = 0.f, hpB = 0.f, hqA = 0.f, hqB = 0.f;
                #pragma unroll
                for (int j = 0; j < 12; ++j) {
                    const int o = 1 + j;
                    const float xe = (o & 1) ? wx[o >> 1].y : wx[o >> 1].x;
                    const float ye = (o & 1) ? wy[o >> 1].y : wy[o >> 1].x;
                    const float pe = fmaf(xe, xe, ye * ye);
                    const float qe = xe * ye;
                    if (j <= 10) {              // tap g[j] for col A
                        hxA = fmaf(g[j], xe, hxA);
                        hyA = fmaf(g[j], ye, hyA);
                        hpA = fmaf(g[j], pe, hpA);
                        hqA = fmaf(g[j], qe, hqA);
                    }
                    if (j >= 1) {               // tap g[j-1] for col B
                        hxB = fmaf(g[j - 1], xe, hxB);
                        hyB = fmaf(g[j - 1], ye, hyB);
                        hpB = fmaf(g[j - 1], pe, hpB);
                        hqB = fmaf(g[j - 1], qe, hqB);
                    }
                }
                rxA[s] = hxA; rxB[s] = hxB;
                ryA[s] = hyA; ryB[s] = hyB;
                rpA[s] = hpA; rpB[s] = hpB;
                rqA[s] = hqA; rqB[s] = hqB;

                if (i >= 10) {                  // output row r0 + i - 10
                    float mxA = 0.f, myA = 0.f, mpA = 0.f, mqA = 0.f;
                    float mxB = 0.f, myB = 0.f, mpB = 0.f, mqB = 0.f;
                    #pragma unroll
                    for (int j = 0; j < 11; ++j) {
                        const int sl = (s + 1 + j) % 11;   // static
                        mxA = fmaf(g[j], rxA[sl], mxA);
                        myA = fmaf(g[j], ryA[sl], myA);
                        mpA = fmaf(g[j], rpA[sl], mpA);
                        mqA = fmaf(g[j], rqA[sl], mqA);
                        mxB = fmaf(g[j], rxB[sl], mxB);
                        myB = fmaf(g[j], ryB[sl], myB);
                        mpB = fmaf(g[j], rpB[sl], mpB);
                        mqB = fmaf(g[j], rqB[sl], mqB);
                    }
                    {
                        const float mux2 = mxA * mxA, muy2 = myA * myA;
                        const float muxy = mxA * myA;
                        const float a    = mux2 + muy2;
                        const float sxy  = mqA - muxy;
                        const float ssum = mpA - a;
                        const float num  = fmaf(2.f, muxy, C1F) * fmaf(2.f, sxy, C2F);
                        const float den  = (a + C1F) * (ssum + C2F);
                        float v = num * __builtin_amdgcn_rcpf(den + EPSF);
                        acc += fminf(fmaxf(v, 0.f), 1.f);
                    }
                    {
                        const float mux2 = mxB * mxB, muy2 = myB * myB;
                        const float muxy = mxB * myB;
                        const float a    = mux2 + muy2;
                        const float sxy  = mqB - muxy;
                        const float ssum = mpB - a;
                        const float num  = fmaf(2.f, muxy, C1F) * fmaf(2.f, sxy, C2F);
                        const float den  = (a + C1F) * (ssum + C2F);
                        float v = num * __builtin_amdgcn_rcpf(den + EPSF);
                        acc += fminf(fmaxf(v, 0.f), 1.f);
                    }
                }
            }
        }
    }

    // wave reduction + one atomic per wave
    #pragma unroll
    for (int off = 32; off > 0; off >>= 1)
        acc += __shfl_down(acc, off, 64);
    if (lane == 0)
        atomicAdd(out, acc * (1.0f / (float)((size_t)NIMG * IMG_H * IMG_W)));
}

extern "C" void kernel_launch(void* const* d_in, const int* in_sizes, int n_in,
                              void* d_out, int out_size, void* d_ws, size_t ws_size,
                              hipStream_t stream) {
    const float* x = (const float*)d_in[0];
    const float* y = (const float*)d_in[1];
    const float* w = (const float*)d_in[2];
    float* out = (float*)d_out;

    // d_out is re-poisoned to 0xAA before every timed launch; zero it first.
    hipMemsetAsync(out, 0, sizeof(float), stream);

    dim3 grid(IMG_H / RROWS, NIMG);    // (32, 32) = 1024 blocks, 4096 waves
    ssim_kernel<<<grid, dim3(NT), 0, stream>>>(x, y, w, out);
}

// Round 4
// 132.492 us; speedup vs baseline: 2.1774x; 2.1774x over previous
//
#include <hip/hip_runtime.h>

// SSIM, N=32 images 512x512 fp32, 11x11 Gaussian (separable via rank-1
// window), zero pad, scalar mean output.
//
// R4: R1 skeleton (proven: 64us, no spill) with its two measured deficits
// fixed:
//  - occupancy: RROWS 64->32 => 2048 blocks = 4096 waves = 16 waves/CU
//  - VALU: stage 4 planes (x, y, p=x^2+y^2, q=x*y) as AoS float4 in LDS,
//    p/q computed ONCE per element at staging (R1 recomputed (x+-y)^2 per
//    tap). Horizontal conv = 11 x (ds_read_b128 + 4 FMA). AoS float4 is
//    stride-16B dense -> conflict-free.
// NO min-waves launch_bounds arg (R3's 64-VGPR cap + 244MB scratch spill).
// Vertical conv via 44-float register ring, mod-11 static by 11x unroll.

#define IMG_H 512
#define IMG_W 512
#define NIMG  32
#define TW    128              // threads = own columns per block
#define RROWS 32               // output rows per block
#define ITERS (RROWS + 10)     // 42 input rows streamed
#define LDSW  (TW + 10)        // 138 staged cols (5-col halo each side)

#define C1F  1.0e-4f
#define C2F  9.0e-4f
#define EPSF 1.0e-8f

__global__ __launch_bounds__(TW) void ssim_kernel(
    const float* __restrict__ xg, const float* __restrict__ yg,
    const float* __restrict__ wg, float* __restrict__ out)
{
    const int t    = threadIdx.x;       // 0..127
    const int band = blockIdx.x;        // 0..3
    const int chnk = blockIdx.y;        // 0..15
    const int img  = blockIdx.z;        // 0..31
    const int c0   = band * TW;
    const int r0   = chnk * RROWS;

    const float* xb = xg + (size_t)img * (IMG_H * IMG_W);
    const float* yb = yg + (size_t)img * (IMG_H * IMG_W);

    __shared__ float4 sq[2][LDSW];      // (x, y, p, q) per column
    __shared__ float wredS[2];

    // 1D taps = row sums of normalized 2D window -> SGPRs via readfirstlane.
    float rs = 0.f;
    {
        const int lane = t & 63;
        if (lane < 11) {
            #pragma unroll
            for (int j = 0; j < 11; ++j) rs += wg[lane * 11 + j];
        }
    }
    float g[11];
    #pragma unroll
    for (int k = 0; k < 11; ++k) {
        int gi = __shfl(__float_as_int(rs), k, 64);
        g[k] = __int_as_float(__builtin_amdgcn_readfirstlane(gi));
    }

    const int colA = c0 + t;                    // always in [0, IMG_W)
    const int  b2     = (t < 5) ? t : (TW + t); // halo buffer slot (t<10)
    const int  colB   = c0 - 5 + b2;
    const bool hasB   = (t < 10);
    const bool colBok = hasB && ((unsigned)colB < IMG_W);

    // vertical register rings: 4 planes x 11 rows = 44 VGPRs
    float rx[11], ry[11], rp[11], rq[11];

    // preload first input row (r0 - 5)
    float lxA, lyA, lxB, lyB;
    {
        const int r = r0 - 5;
        const bool rv = ((unsigned)r < IMG_H);
        const float* xr = xb + (size_t)r * IMG_W;
        const float* yr = yb + (size_t)r * IMG_W;
        lxA = rv ? xr[colA] : 0.f;
        lyA = rv ? yr[colA] : 0.f;
        lxB = (rv && colBok) ? xr[colB] : 0.f;
        lyB = (rv && colBok) ? yr[colB] : 0.f;
    }

    float acc = 0.f;

    for (int ii = 0; ii < 44; ii += 11) {
        #pragma unroll
        for (int s = 0; s < 11; ++s) {
            const int i = ii + s;
            if (i < ITERS) {
                const int pb = i & 1;
                // stage own column (+ halo col for t<10): p,q computed once
                {
                    float4 v;
                    v.x = lxA; v.y = lyA;
                    v.z = fmaf(lxA, lxA, lyA * lyA);
                    v.w = lxA * lyA;
                    sq[pb][5 + t] = v;
                    if (hasB) {
                        float4 h;
                        h.x = lxB; h.y = lyB;
                        h.z = fmaf(lxB, lxB, lyB * lyB);
                        h.w = lxB * lyB;
                        sq[pb][b2] = h;
                    }
                }
                __syncthreads();

                // prefetch next input row (consumed next iteration)
                {
                    const int r = r0 - 4 + i;
                    const bool rv = ((unsigned)r < IMG_H);
                    const float* xr = xb + (size_t)r * IMG_W;
                    const float* yr = yb + (size_t)r * IMG_W;
                    lxA = rv ? xr[colA] : 0.f;
                    lyA = rv ? yr[colA] : 0.f;
                    lxB = (rv && colBok) ? xr[colB] : 0.f;
                    lyB = (rv && colBok) ? yr[colB] : 0.f;
                }

                // horizontal 11-tap conv, 4 planes via b128 window reads
                float hx = 0.f, hy = 0.f, hp = 0.f, hq = 0.f;
                #pragma unroll
                for (int k = 0; k < 11; ++k) {
                    const float4 w = sq[pb][t + k];
                    hx = fmaf(g[k], w.x, hx);
                    hy = fmaf(g[k], w.y, hy);
                    hp = fmaf(g[k], w.z, hp);
                    hq = fmaf(g[k], w.w, hq);
                }
                rx[s] = hx; ry[s] = hy; rp[s] = hp; rq[s] = hq;

                if (i >= 10) {                  // output row r0 + i - 10
                    float mx = 0.f, my = 0.f, mp = 0.f, mq = 0.f;
                    #pragma unroll
                    for (int j = 0; j < 11; ++j) {
                        const int sl = (s + 1 + j) % 11;   // static
                        mx = fmaf(g[j], rx[sl], mx);
                        my = fmaf(g[j], ry[sl], my);
                        mp = fmaf(g[j], rp[sl], mp);
                        mq = fmaf(g[j], rq[sl], mq);
                    }
                    const float mux2 = mx * mx, muy2 = my * my;
                    const float muxy = mx * my;
                    const float a    = mux2 + muy2;
                    const float sxy  = mq - muxy;
                    const float ssum = mp - a;
                    const float num  = fmaf(2.f, muxy, C1F) * fmaf(2.f, sxy, C2F);
                    const float den  = (a + C1F) * (ssum + C2F);
                    float v = num * __builtin_amdgcn_rcpf(den + EPSF);
                    acc += fminf(fmaxf(v, 0.f), 1.f);
                }
            }
        }
    }

    // block reduction: wave shuffle, then 2 slots in LDS, one atomic
    #pragma unroll
    for (int off = 32; off > 0; off >>= 1)
        acc += __shfl_down(acc, off, 64);
    __syncthreads();
    if ((t & 63) == 0) wredS[t >> 6] = acc;
    __syncthreads();
    if (t == 0) {
        const float tot = wredS[0] + wredS[1];
        atomicAdd(out, tot * (1.0f / (float)((size_t)NIMG * IMG_H * IMG_W)));
    }
}

extern "C" void kernel_launch(void* const* d_in, const int* in_sizes, int n_in,
                              void* d_out, int out_size, void* d_ws, size_t ws_size,
                              hipStream_t stream) {
    const float* x = (const float*)d_in[0];
    const float* y = (const float*)d_in[1];
    const float* w = (const float*)d_in[2];
    float* out = (float*)d_out;

    // d_out is re-poisoned to 0xAA before every timed launch; zero it first.
    hipMemsetAsync(out, 0, sizeof(float), stream);

    dim3 grid(IMG_W / TW, IMG_H / RROWS, NIMG);   // (4, 16, 32)
    ssim_kernel<<<grid, dim3(TW), 0, stream>>>(x, y, w, out);
}